// Round 1
// baseline (614.416 us; speedup 1.0000x reference)
//
#include <hip/hip_runtime.h>
#include <math.h>

#define N_PTS 8192
#define KNN 16

// ---------------------------------------------------------------------------
// kNN: exact top-16 by squared distance, reference formula sq_i+sq_j-2*dot.
// 16 queries/block, 16 threads/query. Per-thread sorted top-16 in registers
// (fully unrolled -> static indexing). Shared per-query prune bound G in LDS
// (min over threads' 16th-best) keeps insertions rare. Exact merge at end.
// ---------------------------------------------------------------------------
constexpr int QPB = 16;
constexpr int TPQ = 16;
constexpr int KTILE = 1024;

__global__ __launch_bounds__(256) void knn_kernel(const float* __restrict__ pos,
                                                  int* __restrict__ idx_out)
{
    __shared__ float4 tile[KTILE];            // 16 KB
    __shared__ float  md[QPB][TPQ * KNN];     // 16 KB
    __shared__ int    mi[QPB][TPQ * KNN];     // 16 KB
    __shared__ unsigned gbits[QPB];

    const int tid  = threadIdx.x;
    const int qloc = tid / TPQ;
    const int tq   = tid % TPQ;
    const int q    = blockIdx.x * QPB + qloc;

    if (tid < QPB) gbits[tid] = 0x7f800000u;  // +inf

    const float qx = pos[q * 3 + 0];
    const float qy = pos[q * 3 + 1];
    const float qz = pos[q * 3 + 2];
    const float sqq = qx * qx + qy * qy + qz * qz;

    float dist[KNN];
    int   ind[KNN];
#pragma unroll
    for (int s = 0; s < KNN; ++s) { dist[s] = __uint_as_float(0x7f800000u); ind[s] = 0; }

    for (int base = 0; base < N_PTS; base += KTILE) {
        __syncthreads();
        for (int t = tid; t < KTILE; t += 256) {
            const float x = pos[(base + t) * 3 + 0];
            const float y = pos[(base + t) * 3 + 1];
            const float z = pos[(base + t) * 3 + 2];
            tile[t] = make_float4(x, y, z, x * x + y * y + z * z);
        }
        __syncthreads();
        for (int s = tq; s < KTILE; s += TPQ) {
            const float4 pj = tile[s];
            const float d2 = sqq + pj.w - 2.0f * (qx * pj.x + qy * pj.y + qz * pj.z);
            const float g = __uint_as_float(gbits[qloc]);
            if (d2 < g) {
                const int j = base + s;
#pragma unroll
                for (int p = KNN - 1; p > 0; --p) {
                    if (d2 < dist[p - 1])      { dist[p] = dist[p - 1]; ind[p] = ind[p - 1]; }
                    else if (d2 < dist[p])     { dist[p] = d2;          ind[p] = j; }
                }
                if (d2 < dist[0]) { dist[0] = d2; ind[0] = j; }
                atomicMin(&gbits[qloc], __float_as_uint(dist[KNN - 1]));
            }
        }
    }

#pragma unroll
    for (int s = 0; s < KNN; ++s) { md[qloc][tq * KNN + s] = dist[s]; mi[qloc][tq * KNN + s] = ind[s]; }
    __syncthreads();

    if (tq == 0) {
#pragma unroll
        for (int s = 0; s < KNN; ++s) { dist[s] = __uint_as_float(0x7f800000u); ind[s] = 0; }
        for (int e = 0; e < TPQ * KNN; ++e) {
            const float d2 = md[qloc][e];
            const int   j  = mi[qloc][e];
            if (d2 < dist[KNN - 1]) {
#pragma unroll
                for (int p = KNN - 1; p > 0; --p) {
                    if (d2 < dist[p - 1])      { dist[p] = dist[p - 1]; ind[p] = ind[p - 1]; }
                    else if (d2 < dist[p])     { dist[p] = d2;          ind[p] = j; }
                }
                if (d2 < dist[0]) { dist[0] = d2; ind[0] = j; }
            }
        }
#pragma unroll
        for (int s = 0; s < KNN; ++s) idx_out[q * KNN + s] = ind[s];
    }
}

// ---------------------------------------------------------------------------
// PointNetConv layer: out[i,c] = relu( max_k( relu(msg @ Wa + ba) @ Wb )[k,c] + bb[c] )
// msg[i,k,:] = concat(x[idx[i,k]], pos[idx[i,k]] - pos[i])
// Block handles P=4 points. msg + h staged in LDS; LDS reads in GEMM loops are
// wave-uniform float4 broadcasts (1 ds_read_b128 per 4 FMA).
// ---------------------------------------------------------------------------
template <int CIN, int F, int CMID, int COUT, int P>
__global__ __launch_bounds__(256) void conv_kernel(
    const float* __restrict__ x, const float* __restrict__ pos,
    const int* __restrict__ idx,
    const float* __restrict__ Wa, const float* __restrict__ ba,
    const float* __restrict__ Wb, const float* __restrict__ bb,
    float* __restrict__ out)
{
    constexpr int PK    = P * KNN;          // 64 rows
    constexpr int FPAD  = (F + 3) & ~3;     // 8 or 68
    constexpr int CMP   = CMID + 4;         // padded h stride (16B aligned, bank-staggered)

    __shared__ float msg[PK][FPAD];
    __shared__ float h[PK][CMP];
    __shared__ int   nbr[PK];

    const int tid = threadIdx.x;
    const int i0  = blockIdx.x * P;

    if (tid < PK) nbr[tid] = idx[i0 * KNN + tid];
    __syncthreads();

    // build messages (zero-padded columns F..FPAD)
    for (int e = tid; e < PK * FPAD; e += 256) {
        const int pk = e / FPAD, f = e % FPAD;
        const int p = pk >> 4;
        const int j = nbr[pk];
        float v = 0.0f;
        if (f < CIN)        v = x[j * CIN + f];
        else if (f < F)     v = pos[j * 3 + (f - CIN)] - pos[(i0 + p) * 3 + (f - CIN)];
        msg[pk][f] = v;
    }
    __syncthreads();

    {   // h = relu(msg @ Wa + ba)
        constexpr int NG  = 256 / CMID;     // groups over rows
        constexpr int RPG = PK / NG;        // rows per thread
        const int c = tid % CMID, g = tid / CMID;
        float acc[RPG];
#pragma unroll
        for (int r = 0; r < RPG; ++r) acc[r] = 0.0f;
        for (int fb = 0; fb < FPAD; fb += 4) {
            const float w0 = (fb + 0 < F) ? Wa[(fb + 0) * CMID + c] : 0.0f;
            const float w1 = (fb + 1 < F) ? Wa[(fb + 1) * CMID + c] : 0.0f;
            const float w2 = (fb + 2 < F) ? Wa[(fb + 2) * CMID + c] : 0.0f;
            const float w3 = (fb + 3 < F) ? Wa[(fb + 3) * CMID + c] : 0.0f;
#pragma unroll
            for (int r = 0; r < RPG; ++r) {
                const float4 m4 = *reinterpret_cast<const float4*>(&msg[g * RPG + r][fb]);
                acc[r] = fmaf(m4.x, w0, acc[r]);
                acc[r] = fmaf(m4.y, w1, acc[r]);
                acc[r] = fmaf(m4.z, w2, acc[r]);
                acc[r] = fmaf(m4.w, w3, acc[r]);
            }
        }
        const float bv = ba[c];
#pragma unroll
        for (int r = 0; r < RPG; ++r) h[g * RPG + r][c] = fmaxf(acc[r] + bv, 0.0f);
    }
    __syncthreads();

    {   // out = relu(max_k(h @ Wb) + bb)
        constexpr int NGO = 256 / COUT;     // groups over points
        constexpr int PPT = P / NGO;        // points per thread
        const int c = tid % COUT, g = tid / COUT;
        float s[PPT][KNN];
#pragma unroll
        for (int pp = 0; pp < PPT; ++pp)
#pragma unroll
            for (int k = 0; k < KNN; ++k) s[pp][k] = 0.0f;

        for (int m = 0; m < CMID; m += 4) {
            const float w0 = Wb[(m + 0) * COUT + c];
            const float w1 = Wb[(m + 1) * COUT + c];
            const float w2 = Wb[(m + 2) * COUT + c];
            const float w3 = Wb[(m + 3) * COUT + c];
#pragma unroll
            for (int pp = 0; pp < PPT; ++pp) {
                const int p = g + pp * NGO;
#pragma unroll
                for (int k = 0; k < KNN; ++k) {
                    const float4 h4 = *reinterpret_cast<const float4*>(&h[p * KNN + k][m]);
                    s[pp][k] = fmaf(h4.x, w0, s[pp][k]);
                    s[pp][k] = fmaf(h4.y, w1, s[pp][k]);
                    s[pp][k] = fmaf(h4.z, w2, s[pp][k]);
                    s[pp][k] = fmaf(h4.w, w3, s[pp][k]);
                }
            }
        }
#pragma unroll
        for (int pp = 0; pp < PPT; ++pp) {
            const int p = g + pp * NGO;
            float mx = s[pp][0];
#pragma unroll
            for (int k = 1; k < KNN; ++k) mx = fmaxf(mx, s[pp][k]);
            out[(i0 + p) * COUT + c] = fmaxf(mx + bb[c], 0.0f);
        }
    }
}

extern "C" void kernel_launch(void* const* d_in, const int* in_sizes, int n_in,
                              void* d_out, int out_size, void* d_ws, size_t ws_size,
                              hipStream_t stream)
{
    const float* pos = (const float*)d_in[0];
    const float* W1a = (const float*)d_in[1];
    const float* b1a = (const float*)d_in[2];
    const float* W1b = (const float*)d_in[3];
    const float* b1b = (const float*)d_in[4];
    const float* W2a = (const float*)d_in[5];
    const float* b2a = (const float*)d_in[6];
    const float* W2b = (const float*)d_in[7];
    const float* b2b = (const float*)d_in[8];
    const float* W3a = (const float*)d_in[9];
    const float* b3a = (const float*)d_in[10];
    const float* W3b = (const float*)d_in[11];
    const float* b3b = (const float*)d_in[12];

    float* out = (float*)d_out;
    float* h1 = out;                       // 8192 x 64
    float* h2 = out + N_PTS * 64;          // 8192 x 64
    float* h3 = out + N_PTS * 128;         // 8192 x 128

    int* idx = (int*)d_ws;                 // 8192 x 16 ints

    knn_kernel<<<N_PTS / QPB, 256, 0, stream>>>(pos, idx);

    conv_kernel<3, 6, 64, 64, 4><<<N_PTS / 4, 256, 0, stream>>>(
        pos, pos, idx, W1a, b1a, W1b, b1b, h1);
    conv_kernel<64, 67, 64, 64, 4><<<N_PTS / 4, 256, 0, stream>>>(
        h1, pos, idx, W2a, b2a, W2b, b2b, h2);
    conv_kernel<64, 67, 128, 128, 4><<<N_PTS / 4, 256, 0, stream>>>(
        h2, pos, idx, W3a, b3a, W3b, b3b, h3);
}

// Round 2
// 364.028 us; speedup vs baseline: 1.6878x; 1.6878x over previous
//
#include <hip/hip_runtime.h>
#include <math.h>

#define N_PTS 8192
#define KNN 16

// ---------------------------------------------------------------------------
// pos4 prep: pack (x,y,z, x^2+y^2+z^2) for single-load candidate access.
// ---------------------------------------------------------------------------
__global__ __launch_bounds__(256) void prep_kernel(const float* __restrict__ pos,
                                                   float4* __restrict__ pos4)
{
    const int i = blockIdx.x * 256 + threadIdx.x;
    const float x = pos[i * 3 + 0];
    const float y = pos[i * 3 + 1];
    const float z = pos[i * 3 + 2];
    pos4[i] = make_float4(x, y, z, fmaf(x, x, fmaf(y, y, z * z)));
}

// deterministic d2: identical instruction sequence in every pass
__device__ __forceinline__ float dist2(const float4 a, const float4 b)
{
    const float dot = fmaf(a.x, b.x, fmaf(a.y, b.y, a.z * b.z));
    return fmaf(-2.0f, dot, a.w + b.w);
}

__device__ __forceinline__ unsigned sortkey(const float d2)
{
    unsigned u = __float_as_uint(d2);
    u ^= (unsigned)((int)u >> 31) | 0x80000000u;  // monotone float->uint (handles negatives)
    return u;
}

// ---------------------------------------------------------------------------
// kNN radix-select: 1 wave per query, 4 queries per 256-thread block.
// Pass 1: 2048-bin histogram of key bits [31:21]. Prefix-scan locates the bin
// containing the 16th smallest. (Rare) refine pass on bits [20:13] if the bin
// is too heavy. Pass 2: collect survivors (key <= hi, <=128 of them). Final:
// 16 rounds of wave-wide 64-bit min over (key||idx) packs -> exact top-16,
// ties broken by lowest index. No __syncthreads: all LDS state is wave-local.
// ---------------------------------------------------------------------------
constexpr int CAP = 128;

__global__ __launch_bounds__(256) void knn_kernel(const float4* __restrict__ pos4,
                                                  int* __restrict__ idx_out)
{
    __shared__ unsigned hist[4][2048];              // 32 KB
    __shared__ unsigned long long surv[4][CAP];     // 4 KB
    __shared__ int scnt[4];

    const int tid  = threadIdx.x;
    const int w    = tid >> 6;
    const int lane = tid & 63;
    const int q    = blockIdx.x * 4 + w;

    // zero wave-local state
#pragma unroll
    for (int s = 0; s < 8; ++s)
        *reinterpret_cast<uint4*>(&hist[w][lane * 32 + s * 4]) = make_uint4(0, 0, 0, 0);
    if (lane == 0) scnt[w] = 0;
    asm volatile("s_waitcnt lgkmcnt(0)" ::: "memory");

    const float4 qp = pos4[q];

    // ---- pass 1: histogram bits [31:21] ----
#pragma unroll 8
    for (int t = 0; t < N_PTS / 64; ++t) {
        const float4 p = pos4[t * 64 + lane];
        const unsigned u = sortkey(dist2(qp, p));
        atomicAdd(&hist[w][u >> 21], 1u);
    }
    asm volatile("s_waitcnt lgkmcnt(0)" ::: "memory");

    // ---- wave prefix over 2048 bins (lane owns bins [lane*32, lane*32+32)) ----
    unsigned lsum = 0;
#pragma unroll
    for (int s = 0; s < 32; ++s) lsum += hist[w][lane * 32 + s];
    unsigned pre = lsum;
#pragma unroll
    for (int d = 1; d < 64; d <<= 1) {
        const unsigned t = __shfl_up(pre, d);
        if (lane >= d) pre += t;
    }
    const unsigned excl = pre - lsum;              // keys in bins before this lane's chunk
    const bool cross = (excl < KNN) && (excl + lsum >= KNN);
    const unsigned long long bal = __ballot(cross);
    const int L = __ffsll(bal) - 1;
    unsigned cb = __shfl(excl, L);                 // count strictly below chosen bin (builds up)
    int b = -1; unsigned bc = 0;
    for (int s = 0; s < 32; ++s) {                 // redundant uniform scan of lane L's chunk
        const unsigned hv = hist[w][L * 32 + s];
        if (b < 0) {
            if (cb + hv >= KNN) { b = L * 32 + s; bc = hv; }
            else cb += hv;
        }
    }
    unsigned hi = ((unsigned)b << 21) | 0x1FFFFFu;

    // ---- rare refinement on bits [20:13] if selected bin too heavy ----
    if (cb + bc > (unsigned)CAP - 1) {
        for (int s = lane; s < 256; s += 64) hist[w][s] = 0;
        asm volatile("s_waitcnt lgkmcnt(0)" ::: "memory");
#pragma unroll 4
        for (int t = 0; t < N_PTS / 64; ++t) {
            const float4 p = pos4[t * 64 + lane];
            const unsigned u = sortkey(dist2(qp, p));
            if ((u >> 21) == (unsigned)b) atomicAdd(&hist[w][(u >> 13) & 255u], 1u);
        }
        asm volatile("s_waitcnt lgkmcnt(0)" ::: "memory");
        unsigned ls2 = 0;
#pragma unroll
        for (int s = 0; s < 4; ++s) ls2 += hist[w][lane * 4 + s];
        unsigned pre2 = ls2;
#pragma unroll
        for (int d = 1; d < 64; d <<= 1) {
            const unsigned t2 = __shfl_up(pre2, d);
            if (lane >= d) pre2 += t2;
        }
        const unsigned excl2 = pre2 - ls2;
        const unsigned R = KNN - cb;
        const bool cr2 = (excl2 < R) && (excl2 + ls2 >= R);
        const unsigned long long bal2 = __ballot(cr2);
        const int L2 = __ffsll(bal2) - 1;
        unsigned cb2 = __shfl(excl2, L2);
        int sb = -1;
        for (int s = 0; s < 4; ++s) {
            const unsigned hv = hist[w][L2 * 4 + s];
            if (sb < 0) {
                if (cb2 + hv >= R) sb = L2 * 4 + s;
                else cb2 += hv;
            }
        }
        hi = ((unsigned)b << 21) | ((unsigned)sb << 13) | 0x1FFFu;
    }

    // ---- pass 2: collect survivors ----
#pragma unroll 4
    for (int t = 0; t < N_PTS / 64; ++t) {
        const int j = t * 64 + lane;
        const float4 p = pos4[j];
        const unsigned u = sortkey(dist2(qp, p));
        if (u <= hi) {
            const int slot = atomicAdd(&scnt[w], 1);
            if (slot < CAP) surv[w][slot] = ((unsigned long long)u << 32) | (unsigned)j;
        }
    }
    asm volatile("s_waitcnt lgkmcnt(0)" ::: "memory");

    // ---- exact top-16 of survivors: 16 rounds of wave-wide 64-bit min ----
    const int n = min(scnt[w], CAP);
    unsigned long long c0 = (lane < n) ? surv[w][lane] : ~0ull;
    unsigned long long c1 = (lane + 64 < n) ? surv[w][lane + 64] : ~0ull;
    for (int r = 0; r < KNN; ++r) {
        unsigned long long m = c0 < c1 ? c0 : c1;
#pragma unroll
        for (int d = 32; d >= 1; d >>= 1) {
            const unsigned long long o = __shfl_xor(m, d);
            if (o < m) m = o;
        }
        if (c0 == m) c0 = ~0ull;
        else if (c1 == m) c1 = ~0ull;
        if (lane == 0) idx_out[q * KNN + r] = (int)(unsigned)(m & 0xFFFFFFFFu);
    }
}

// ---------------------------------------------------------------------------
// PointNetConv layer (unchanged from R0): out = relu(max_k(relu(msg@Wa+ba)@Wb)+bb)
// ---------------------------------------------------------------------------
template <int CIN, int F, int CMID, int COUT, int P>
__global__ __launch_bounds__(256) void conv_kernel(
    const float* __restrict__ x, const float* __restrict__ pos,
    const int* __restrict__ idx,
    const float* __restrict__ Wa, const float* __restrict__ ba,
    const float* __restrict__ Wb, const float* __restrict__ bb,
    float* __restrict__ out)
{
    constexpr int PK    = P * KNN;          // 64 rows
    constexpr int FPAD  = (F + 3) & ~3;     // 8 or 68
    constexpr int CMP   = CMID + 4;

    __shared__ float msg[PK][FPAD];
    __shared__ float h[PK][CMP];
    __shared__ int   nbr[PK];

    const int tid = threadIdx.x;
    const int i0  = blockIdx.x * P;

    if (tid < PK) nbr[tid] = idx[i0 * KNN + tid];
    __syncthreads();

    for (int e = tid; e < PK * FPAD; e += 256) {
        const int pk = e / FPAD, f = e % FPAD;
        const int p = pk >> 4;
        const int j = nbr[pk];
        float v = 0.0f;
        if (f < CIN)        v = x[j * CIN + f];
        else if (f < F)     v = pos[j * 3 + (f - CIN)] - pos[(i0 + p) * 3 + (f - CIN)];
        msg[pk][f] = v;
    }
    __syncthreads();

    {   // h = relu(msg @ Wa + ba)
        constexpr int NG  = 256 / CMID;
        constexpr int RPG = PK / NG;
        const int c = tid % CMID, g = tid / CMID;
        float acc[RPG];
#pragma unroll
        for (int r = 0; r < RPG; ++r) acc[r] = 0.0f;
        for (int fb = 0; fb < FPAD; fb += 4) {
            const float w0 = (fb + 0 < F) ? Wa[(fb + 0) * CMID + c] : 0.0f;
            const float w1 = (fb + 1 < F) ? Wa[(fb + 1) * CMID + c] : 0.0f;
            const float w2 = (fb + 2 < F) ? Wa[(fb + 2) * CMID + c] : 0.0f;
            const float w3 = (fb + 3 < F) ? Wa[(fb + 3) * CMID + c] : 0.0f;
#pragma unroll
            for (int r = 0; r < RPG; ++r) {
                const float4 m4 = *reinterpret_cast<const float4*>(&msg[g * RPG + r][fb]);
                acc[r] = fmaf(m4.x, w0, acc[r]);
                acc[r] = fmaf(m4.y, w1, acc[r]);
                acc[r] = fmaf(m4.z, w2, acc[r]);
                acc[r] = fmaf(m4.w, w3, acc[r]);
            }
        }
        const float bv = ba[c];
#pragma unroll
        for (int r = 0; r < RPG; ++r) h[g * RPG + r][c] = fmaxf(acc[r] + bv, 0.0f);
    }
    __syncthreads();

    {   // out = relu(max_k(h @ Wb) + bb)
        constexpr int NGO = 256 / COUT;
        constexpr int PPT = P / NGO;
        const int c = tid % COUT, g = tid / COUT;
        float s[PPT][KNN];
#pragma unroll
        for (int pp = 0; pp < PPT; ++pp)
#pragma unroll
            for (int k = 0; k < KNN; ++k) s[pp][k] = 0.0f;

        for (int m = 0; m < CMID; m += 4) {
            const float w0 = Wb[(m + 0) * COUT + c];
            const float w1 = Wb[(m + 1) * COUT + c];
            const float w2 = Wb[(m + 2) * COUT + c];
            const float w3 = Wb[(m + 3) * COUT + c];
#pragma unroll
            for (int pp = 0; pp < PPT; ++pp) {
                const int p = g + pp * NGO;
#pragma unroll
                for (int k = 0; k < KNN; ++k) {
                    const float4 h4 = *reinterpret_cast<const float4*>(&h[p * KNN + k][m]);
                    s[pp][k] = fmaf(h4.x, w0, s[pp][k]);
                    s[pp][k] = fmaf(h4.y, w1, s[pp][k]);
                    s[pp][k] = fmaf(h4.z, w2, s[pp][k]);
                    s[pp][k] = fmaf(h4.w, w3, s[pp][k]);
                }
            }
        }
#pragma unroll
        for (int pp = 0; pp < PPT; ++pp) {
            const int p = g + pp * NGO;
            float mx = s[pp][0];
#pragma unroll
            for (int k = 1; k < KNN; ++k) mx = fmaxf(mx, s[pp][k]);
            out[(i0 + p) * COUT + c] = fmaxf(mx + bb[c], 0.0f);
        }
    }
}

extern "C" void kernel_launch(void* const* d_in, const int* in_sizes, int n_in,
                              void* d_out, int out_size, void* d_ws, size_t ws_size,
                              hipStream_t stream)
{
    const float* pos = (const float*)d_in[0];
    const float* W1a = (const float*)d_in[1];
    const float* b1a = (const float*)d_in[2];
    const float* W1b = (const float*)d_in[3];
    const float* b1b = (const float*)d_in[4];
    const float* W2a = (const float*)d_in[5];
    const float* b2a = (const float*)d_in[6];
    const float* W2b = (const float*)d_in[7];
    const float* b2b = (const float*)d_in[8];
    const float* W3a = (const float*)d_in[9];
    const float* b3a = (const float*)d_in[10];
    const float* W3b = (const float*)d_in[11];
    const float* b3b = (const float*)d_in[12];

    float* out = (float*)d_out;
    float* h1 = out;                       // 8192 x 64
    float* h2 = out + N_PTS * 64;          // 8192 x 64
    float* h3 = out + N_PTS * 128;         // 8192 x 128

    int* idx = (int*)d_ws;                 // 8192 x 16 ints

    // pos4 scratch lives at the head of h3's region: dead before conv3 writes h3
    float4* pos4 = (float4*)h3;

    prep_kernel<<<N_PTS / 256, 256, 0, stream>>>(pos, pos4);
    knn_kernel<<<N_PTS / 4, 256, 0, stream>>>(pos4, idx);

    conv_kernel<3, 6, 64, 64, 4><<<N_PTS / 4, 256, 0, stream>>>(
        pos, pos, idx, W1a, b1a, W1b, b1b, h1);
    conv_kernel<64, 67, 64, 64, 4><<<N_PTS / 4, 256, 0, stream>>>(
        h1, pos, idx, W2a, b2a, W2b, b2b, h2);
    conv_kernel<64, 67, 128, 128, 4><<<N_PTS / 4, 256, 0, stream>>>(
        h2, pos, idx, W3a, b3a, W3b, b3b, h3);
}

// Round 3
// 166.451 us; speedup vs baseline: 3.6913x; 2.1870x over previous
//
#include <hip/hip_runtime.h>
#include <math.h>

#define N_PTS 8192
#define KNN 16

typedef __attribute__((ext_vector_type(8))) short bf16x8;
typedef __attribute__((ext_vector_type(4))) float f32x4v;

__device__ __forceinline__ unsigned short f2bf(float f)
{
    unsigned u = __float_as_uint(f);
    u = u + 0x7fffu + ((u >> 16) & 1u);       // round-to-nearest-even
    return (unsigned short)(u >> 16);
}
__device__ __forceinline__ unsigned pack2(float a, float b)
{
    return (unsigned)f2bf(a) | ((unsigned)f2bf(b) << 16);
}

// ---------------------------------------------------------------------------
// pos4 prep
// ---------------------------------------------------------------------------
__global__ __launch_bounds__(256) void prep_kernel(const float* __restrict__ pos,
                                                   float4* __restrict__ pos4)
{
    const int i = blockIdx.x * 256 + threadIdx.x;
    const float x = pos[i * 3 + 0];
    const float y = pos[i * 3 + 1];
    const float z = pos[i * 3 + 2];
    pos4[i] = make_float4(x, y, z, fmaf(x, x, fmaf(y, y, z * z)));
}

// ---------------------------------------------------------------------------
// Weight prep: pack W (K x N, f32, row-major) into MFMA B-fragment layout,
// bf16. Frag (ks, nt): lane l holds B[ks*32 + (l>>4)*8 + j][nt*16 + (l&15)],
// j=0..7, as 4 dwords. Global frag index == blockIdx.x (64 thr/block).
// ---------------------------------------------------------------------------
__global__ __launch_bounds__(64) void prep_weights(
    const float* __restrict__ w1a, const float* __restrict__ w1b,
    const float* __restrict__ w2a, const float* __restrict__ w2b,
    const float* __restrict__ w3a, const float* __restrict__ w3b,
    uint4* __restrict__ dst)
{
    const float* Ws[6] = {w1a, w1b, w2a, w2b, w3a, w3b};
    const int Kd[6] = {6, 64, 67, 64, 67, 128};
    const int Nd[6] = {64, 64, 64, 64, 128, 128};
    const int start[7] = {0, 4, 12, 24, 32, 56, 88};

    const int b = blockIdx.x;
    int m = 0;
    while (b >= start[m + 1]) ++m;
    const int f  = b - start[m];
    const int NT = Nd[m] / 16;
    const int ks = f / NT, nt = f % NT;

    const int lane = threadIdx.x;
    const int c  = nt * 16 + (lane & 15);
    const int k0 = ks * 32 + (lane >> 4) * 8;
    const int K = Kd[m], N = Nd[m];
    const float* W = Ws[m];

    float v[8];
#pragma unroll
    for (int j = 0; j < 8; ++j) {
        const int kk = k0 + j;
        v[j] = (kk < K) ? W[kk * N + c] : 0.0f;
    }
    uint4 o;
    o.x = pack2(v[0], v[1]); o.y = pack2(v[2], v[3]);
    o.z = pack2(v[4], v[5]); o.w = pack2(v[6], v[7]);
    dst[b * 64 + lane] = o;
}

// ---------------------------------------------------------------------------
// kNN radix-select (unchanged from R1)
// ---------------------------------------------------------------------------
__device__ __forceinline__ float dist2(const float4 a, const float4 b)
{
    const float dot = fmaf(a.x, b.x, fmaf(a.y, b.y, a.z * b.z));
    return fmaf(-2.0f, dot, a.w + b.w);
}
__device__ __forceinline__ unsigned sortkey(const float d2)
{
    unsigned u = __float_as_uint(d2);
    u ^= (unsigned)((int)u >> 31) | 0x80000000u;
    return u;
}

constexpr int CAP = 128;

__global__ __launch_bounds__(256) void knn_kernel(const float4* __restrict__ pos4,
                                                  int* __restrict__ idx_out)
{
    __shared__ unsigned hist[4][2048];
    __shared__ unsigned long long surv[4][CAP];
    __shared__ int scnt[4];

    const int tid  = threadIdx.x;
    const int w    = tid >> 6;
    const int lane = tid & 63;
    const int q    = blockIdx.x * 4 + w;

#pragma unroll
    for (int s = 0; s < 8; ++s)
        *reinterpret_cast<uint4*>(&hist[w][lane * 32 + s * 4]) = make_uint4(0, 0, 0, 0);
    if (lane == 0) scnt[w] = 0;
    asm volatile("s_waitcnt lgkmcnt(0)" ::: "memory");

    const float4 qp = pos4[q];

#pragma unroll 8
    for (int t = 0; t < N_PTS / 64; ++t) {
        const float4 p = pos4[t * 64 + lane];
        const unsigned u = sortkey(dist2(qp, p));
        atomicAdd(&hist[w][u >> 21], 1u);
    }
    asm volatile("s_waitcnt lgkmcnt(0)" ::: "memory");

    unsigned lsum = 0;
#pragma unroll
    for (int s = 0; s < 32; ++s) lsum += hist[w][lane * 32 + s];
    unsigned pre = lsum;
#pragma unroll
    for (int d = 1; d < 64; d <<= 1) {
        const unsigned t = __shfl_up(pre, d);
        if (lane >= d) pre += t;
    }
    const unsigned excl = pre - lsum;
    const bool cross = (excl < KNN) && (excl + lsum >= KNN);
    const unsigned long long bal = __ballot(cross);
    const int L = __ffsll(bal) - 1;
    unsigned cb = __shfl(excl, L);
    int b = -1; unsigned bc = 0;
    for (int s = 0; s < 32; ++s) {
        const unsigned hv = hist[w][L * 32 + s];
        if (b < 0) {
            if (cb + hv >= KNN) { b = L * 32 + s; bc = hv; }
            else cb += hv;
        }
    }
    unsigned hi = ((unsigned)b << 21) | 0x1FFFFFu;

    if (cb + bc > (unsigned)CAP - 1) {
        for (int s = lane; s < 256; s += 64) hist[w][s] = 0;
        asm volatile("s_waitcnt lgkmcnt(0)" ::: "memory");
#pragma unroll 4
        for (int t = 0; t < N_PTS / 64; ++t) {
            const float4 p = pos4[t * 64 + lane];
            const unsigned u = sortkey(dist2(qp, p));
            if ((u >> 21) == (unsigned)b) atomicAdd(&hist[w][(u >> 13) & 255u], 1u);
        }
        asm volatile("s_waitcnt lgkmcnt(0)" ::: "memory");
        unsigned ls2 = 0;
#pragma unroll
        for (int s = 0; s < 4; ++s) ls2 += hist[w][lane * 4 + s];
        unsigned pre2 = ls2;
#pragma unroll
        for (int d = 1; d < 64; d <<= 1) {
            const unsigned t2 = __shfl_up(pre2, d);
            if (lane >= d) pre2 += t2;
        }
        const unsigned excl2 = pre2 - ls2;
        const unsigned R = KNN - cb;
        const bool cr2 = (excl2 < R) && (excl2 + ls2 >= R);
        const unsigned long long bal2 = __ballot(cr2);
        const int L2 = __ffsll(bal2) - 1;
        unsigned cb2 = __shfl(excl2, L2);
        int sb = -1;
        for (int s = 0; s < 4; ++s) {
            const unsigned hv = hist[w][L2 * 4 + s];
            if (sb < 0) {
                if (cb2 + hv >= R) sb = L2 * 4 + s;
                else cb2 += hv;
            }
        }
        hi = ((unsigned)b << 21) | ((unsigned)sb << 13) | 0x1FFFu;
    }

#pragma unroll 4
    for (int t = 0; t < N_PTS / 64; ++t) {
        const int j = t * 64 + lane;
        const float4 p = pos4[j];
        const unsigned u = sortkey(dist2(qp, p));
        if (u <= hi) {
            const int slot = atomicAdd(&scnt[w], 1);
            if (slot < CAP) surv[w][slot] = ((unsigned long long)u << 32) | (unsigned)j;
        }
    }
    asm volatile("s_waitcnt lgkmcnt(0)" ::: "memory");

    const int n = min(scnt[w], CAP);
    unsigned long long c0 = (lane < n) ? surv[w][lane] : ~0ull;
    unsigned long long c1 = (lane + 64 < n) ? surv[w][lane + 64] : ~0ull;
    for (int r = 0; r < KNN; ++r) {
        unsigned long long m = c0 < c1 ? c0 : c1;
#pragma unroll
        for (int d = 32; d >= 1; d >>= 1) {
            const unsigned long long o = __shfl_xor(m, d);
            if (o < m) m = o;
        }
        if (c0 == m) c0 = ~0ull;
        else if (c1 == m) c1 = ~0ull;
        if (lane == 0) idx_out[q * KNN + r] = (int)(unsigned)(m & 0xFFFFFFFFu);
    }
}

// ---------------------------------------------------------------------------
// MFMA PointNetConv. Block: PB=8 points -> M=128 msg rows. msg/h in LDS bf16
// (stride K+8: 16B-aligned, ~2-way banks). Weights read as pre-packed B-frags
// (1 dwordx4/frag/lane). Waves: WM x WN split of (M-tiles x N-tiles).
// GEMM1: h = relu(msg @ Wa + ba); GEMM2: out = relu(max_rows(htile @ Wb) + bb).
// MFMA 16x16x32 bf16: A row=lane&15, k=(lane>>4)*8+j; B col=lane&15 same k;
// D col=lane&15, row=(lane>>4)*4+r. One D tile = one point's 16 neighbors.
// ---------------------------------------------------------------------------
template <int CIN, int CMID, int COUT, int WM, int WN>
__global__ __launch_bounds__(256) void conv_mfma(
    const float* __restrict__ x, const float* __restrict__ pos,
    const int* __restrict__ idx,
    const uint4* __restrict__ fA, const float* __restrict__ ba,
    const uint4* __restrict__ fB, const float* __restrict__ bb,
    float* __restrict__ out)
{
    constexpr int PB  = 8, M = 128;
    constexpr int K1  = (CIN + 3 + 31) & ~31;   // 32 or 96
    constexpr int KS1 = K1 / 32;
    constexpr int KP1 = K1 + 8;
    constexpr int KS2 = CMID / 32;
    constexpr int KP2 = CMID + 8;
    constexpr int NT  = COUT / 16;
    constexpr int NTW = NT / WN;                // 4
    constexpr int MFW = (M / 16) / WM;          // 2 or 4

    __shared__ unsigned short msg[M][KP1];
    __shared__ unsigned short hbuf[M][KP2];
    __shared__ int nbr[M];

    const int tid  = threadIdx.x;
    const int lane = tid & 63;
    const int w    = tid >> 6;
    const int wm   = w / WN, wn = w % WN;
    const int i0   = blockIdx.x * PB;

    if (tid < M) nbr[tid] = idx[i0 * KNN + tid];
    __syncthreads();

    // ---- build msg (bf16) ----
    if constexpr (CIN == 3) {
        if (tid < M) {
            const int row = tid, p = row >> 4, j = nbr[row];
            const float ax = pos[j * 3 + 0], ay = pos[j * 3 + 1], az = pos[j * 3 + 2];
            const float bx = pos[(i0 + p) * 3 + 0], by = pos[(i0 + p) * 3 + 1],
                        bz = pos[(i0 + p) * 3 + 2];
            uint4 c0;
            c0.x = pack2(ax, ay);
            c0.y = pack2(az, ax - bx);
            c0.z = pack2(ay - by, az - bz);
            c0.w = 0u;
            *reinterpret_cast<uint4*>(&msg[row][0]) = c0;
            const uint4 z = make_uint4(0, 0, 0, 0);
            *reinterpret_cast<uint4*>(&msg[row][8])  = z;
            *reinterpret_cast<uint4*>(&msg[row][16]) = z;
            *reinterpret_cast<uint4*>(&msg[row][24]) = z;
        }
    } else {
        const int row = tid >> 1, hh = tid & 1;
        const int j = nbr[row];
        const float* xr = x + j * CIN + hh * 32;
#pragma unroll
        for (int cc = 0; cc < 32; cc += 8) {
            const float4 f0 = *reinterpret_cast<const float4*>(xr + cc);
            const float4 f1 = *reinterpret_cast<const float4*>(xr + cc + 4);
            uint4 o;
            o.x = pack2(f0.x, f0.y); o.y = pack2(f0.z, f0.w);
            o.z = pack2(f1.x, f1.y); o.w = pack2(f1.z, f1.w);
            *reinterpret_cast<uint4*>(&msg[row][hh * 32 + cc]) = o;
        }
        if (hh) {
            const int p = row >> 4;
            const float rx = pos[j * 3 + 0] - pos[(i0 + p) * 3 + 0];
            const float ry = pos[j * 3 + 1] - pos[(i0 + p) * 3 + 1];
            const float rz = pos[j * 3 + 2] - pos[(i0 + p) * 3 + 2];
            uint4 c0;
            c0.x = pack2(rx, ry);
            c0.y = pack2(rz, 0.0f);
            c0.z = 0u; c0.w = 0u;
            *reinterpret_cast<uint4*>(&msg[row][64]) = c0;
            const uint4 z = make_uint4(0, 0, 0, 0);
            *reinterpret_cast<uint4*>(&msg[row][72]) = z;
            *reinterpret_cast<uint4*>(&msg[row][80]) = z;
            *reinterpret_cast<uint4*>(&msg[row][88]) = z;
        }
    }
    __syncthreads();

    // ---- GEMM1: h = relu(msg @ Wa + ba) ----
    {
        uint4 b1[KS1][NTW];
#pragma unroll
        for (int ks = 0; ks < KS1; ++ks)
#pragma unroll
            for (int nt = 0; nt < NTW; ++nt)
                b1[ks][nt] = fA[(ks * NT + wn * NTW + nt) * 64 + lane];

        f32x4v acc[MFW][NTW];
#pragma unroll
        for (int mf = 0; mf < MFW; ++mf)
#pragma unroll
            for (int nt = 0; nt < NTW; ++nt) acc[mf][nt] = (f32x4v)0.0f;

#pragma unroll
        for (int mf = 0; mf < MFW; ++mf) {
            bf16x8 a[KS1];
#pragma unroll
            for (int ks = 0; ks < KS1; ++ks)
                a[ks] = *reinterpret_cast<const bf16x8*>(
                    &msg[(wm * MFW + mf) * 16 + (lane & 15)][ks * 32 + (lane >> 4) * 8]);
#pragma unroll
            for (int nt = 0; nt < NTW; ++nt)
#pragma unroll
                for (int ks = 0; ks < KS1; ++ks)
                    acc[mf][nt] = __builtin_amdgcn_mfma_f32_16x16x32_bf16(
                        a[ks], __builtin_bit_cast(bf16x8, b1[ks][nt]), acc[mf][nt], 0, 0, 0);
        }

        float bav[NTW];
#pragma unroll
        for (int nt = 0; nt < NTW; ++nt) bav[nt] = ba[(wn * NTW + nt) * 16 + (lane & 15)];

#pragma unroll
        for (int mf = 0; mf < MFW; ++mf)
#pragma unroll
            for (int nt = 0; nt < NTW; ++nt)
#pragma unroll
                for (int r = 0; r < 4; ++r) {
                    const float v = fmaxf(acc[mf][nt][r] + bav[nt], 0.0f);
                    hbuf[(wm * MFW + mf) * 16 + (lane >> 4) * 4 + r]
                        [(wn * NTW + nt) * 16 + (lane & 15)] = f2bf(v);
                }
    }
    __syncthreads();

    // ---- GEMM2: out = relu(max_k(htile @ Wb) + bb) ----
    {
        uint4 b2[KS2][NTW];
#pragma unroll
        for (int ks = 0; ks < KS2; ++ks)
#pragma unroll
            for (int nt = 0; nt < NTW; ++nt)
                b2[ks][nt] = fB[(ks * NT + wn * NTW + nt) * 64 + lane];

        f32x4v acc[MFW][NTW];
#pragma unroll
        for (int mf = 0; mf < MFW; ++mf)
#pragma unroll
            for (int nt = 0; nt < NTW; ++nt) acc[mf][nt] = (f32x4v)0.0f;

#pragma unroll
        for (int mf = 0; mf < MFW; ++mf) {
            bf16x8 a[KS2];
#pragma unroll
            for (int ks = 0; ks < KS2; ++ks)
                a[ks] = *reinterpret_cast<const bf16x8*>(
                    &hbuf[(wm * MFW + mf) * 16 + (lane & 15)][ks * 32 + (lane >> 4) * 8]);
#pragma unroll
            for (int nt = 0; nt < NTW; ++nt)
#pragma unroll
                for (int ks = 0; ks < KS2; ++ks)
                    acc[mf][nt] = __builtin_amdgcn_mfma_f32_16x16x32_bf16(
                        a[ks], __builtin_bit_cast(bf16x8, b2[ks][nt]), acc[mf][nt], 0, 0, 0);
        }

        float bbv[NTW];
#pragma unroll
        for (int nt = 0; nt < NTW; ++nt) bbv[nt] = bb[(wn * NTW + nt) * 16 + (lane & 15)];

#pragma unroll
        for (int mf = 0; mf < MFW; ++mf)
#pragma unroll
            for (int nt = 0; nt < NTW; ++nt) {
                const f32x4v t = acc[mf][nt];
                float m0 = fmaxf(fmaxf(t[0], t[1]), fmaxf(t[2], t[3]));
                m0 = fmaxf(m0, __shfl_xor(m0, 16));
                m0 = fmaxf(m0, __shfl_xor(m0, 32));
                const float v = fmaxf(m0 + bbv[nt], 0.0f);
                if (lane < 16)
                    out[(i0 + wm * MFW + mf) * COUT + (wn * NTW + nt) * 16 + lane] = v;
            }
    }
}

extern "C" void kernel_launch(void* const* d_in, const int* in_sizes, int n_in,
                              void* d_out, int out_size, void* d_ws, size_t ws_size,
                              hipStream_t stream)
{
    const float* pos = (const float*)d_in[0];
    const float* W1a = (const float*)d_in[1];
    const float* b1a = (const float*)d_in[2];
    const float* W1b = (const float*)d_in[3];
    const float* b1b = (const float*)d_in[4];
    const float* W2a = (const float*)d_in[5];
    const float* b2a = (const float*)d_in[6];
    const float* W2b = (const float*)d_in[7];
    const float* b2b = (const float*)d_in[8];
    const float* W3a = (const float*)d_in[9];
    const float* b3a = (const float*)d_in[10];
    const float* W3b = (const float*)d_in[11];
    const float* b3b = (const float*)d_in[12];

    float* out = (float*)d_out;
    float* h1 = out;                        // 8192 x 64
    float* h2 = out + N_PTS * 64;           // 8192 x 64
    float* h3 = out + N_PTS * 128;          // 8192 x 128

    int*   idx     = (int*)d_ws;                                   // 512 KB
    uint4* wsFrags = (uint4*)((char*)d_ws + N_PTS * KNN * 4);      // 88 KB

    // pos4 scratch in h3 region (dead before conv3 writes h3)
    float4* pos4 = (float4*)h3;

    prep_weights<<<88, 64, 0, stream>>>(W1a, W1b, W2a, W2b, W3a, W3b, wsFrags);
    prep_kernel<<<N_PTS / 256, 256, 0, stream>>>(pos, pos4);
    knn_kernel<<<N_PTS / 4, 256, 0, stream>>>(pos4, idx);

    const uint4* fW1a = wsFrags + 0 * 64;
    const uint4* fW1b = wsFrags + 4 * 64;
    const uint4* fW2a = wsFrags + 12 * 64;
    const uint4* fW2b = wsFrags + 24 * 64;
    const uint4* fW3a = wsFrags + 32 * 64;
    const uint4* fW3b = wsFrags + 56 * 64;

    conv_mfma<3, 64, 64, 4, 1><<<N_PTS / 8, 256, 0, stream>>>(
        pos, pos, idx, fW1a, b1a, fW1b, b1b, h1);
    conv_mfma<64, 64, 64, 4, 1><<<N_PTS / 8, 256, 0, stream>>>(
        h1, pos, idx, fW2a, b2a, fW2b, b2b, h2);
    conv_mfma<64, 128, 128, 2, 2><<<N_PTS / 8, 256, 0, stream>>>(
        h2, pos, idx, fW3a, b3a, fW3b, b3b, h3);
}

// Round 4
// 119.588 us; speedup vs baseline: 5.1378x; 1.3919x over previous
//
#include <hip/hip_runtime.h>
#include <math.h>

#define N_PTS 8192
#define KNN 16

typedef __attribute__((ext_vector_type(8))) short bf16x8;
typedef __attribute__((ext_vector_type(4))) float f32x4v;

__device__ __forceinline__ unsigned short f2bf(float f)
{
    unsigned u = __float_as_uint(f);
    u = u + 0x7fffu + ((u >> 16) & 1u);       // round-to-nearest-even
    return (unsigned short)(u >> 16);
}
__device__ __forceinline__ unsigned pack2(float a, float b)
{
    return (unsigned)f2bf(a) | ((unsigned)f2bf(b) << 16);
}

// ---------------------------------------------------------------------------
// pos4 prep
// ---------------------------------------------------------------------------
__global__ __launch_bounds__(256) void prep_kernel(const float* __restrict__ pos,
                                                   float4* __restrict__ pos4)
{
    const int i = blockIdx.x * 256 + threadIdx.x;
    const float x = pos[i * 3 + 0];
    const float y = pos[i * 3 + 1];
    const float z = pos[i * 3 + 2];
    pos4[i] = make_float4(x, y, z, fmaf(x, x, fmaf(y, y, z * z)));
}

// ---------------------------------------------------------------------------
// Weight prep: pack W (K x N, f32, row-major) into MFMA B-fragment layout.
// ---------------------------------------------------------------------------
__global__ __launch_bounds__(64) void prep_weights(
    const float* __restrict__ w1a, const float* __restrict__ w1b,
    const float* __restrict__ w2a, const float* __restrict__ w2b,
    const float* __restrict__ w3a, const float* __restrict__ w3b,
    uint4* __restrict__ dst)
{
    const float* Ws[6] = {w1a, w1b, w2a, w2b, w3a, w3b};
    const int Kd[6] = {6, 64, 67, 64, 67, 128};
    const int Nd[6] = {64, 64, 64, 64, 128, 128};
    const int start[7] = {0, 4, 12, 24, 32, 56, 88};

    const int b = blockIdx.x;
    int m = 0;
    while (b >= start[m + 1]) ++m;
    const int f  = b - start[m];
    const int NT = Nd[m] / 16;
    const int ks = f / NT, nt = f % NT;

    const int lane = threadIdx.x;
    const int c  = nt * 16 + (lane & 15);
    const int k0 = ks * 32 + (lane >> 4) * 8;
    const int K = Kd[m], N = Nd[m];
    const float* W = Ws[m];

    float v[8];
#pragma unroll
    for (int j = 0; j < 8; ++j) {
        const int kk = k0 + j;
        v[j] = (kk < K) ? W[kk * N + c] : 0.0f;
    }
    uint4 o;
    o.x = pack2(v[0], v[1]); o.y = pack2(v[2], v[3]);
    o.z = pack2(v[4], v[5]); o.w = pack2(v[6], v[7]);
    dst[b * 64 + lane] = o;
}

// ---------------------------------------------------------------------------
// kNN, threshold-select version. 4 queries per wave, 4 waves per block.
// Pass 1: per-lane min of d2 over lane-partitioned candidates (branchless,
// no LDS). T = 16th smallest of the 64 lane-mins (cross-lane bitonic sort):
// the 16 smallest lane-mins are 16 DISTINCT points => T bounds the true 16th.
// Pass 2: collect survivors d2 <= T (expected ~20, CAP=128 safe to ~1e-50).
// Final: exact top-16 via 16 rounds of wave-wide u64 min (key||idx), ties by
// lowest index. d2 recomputed with identical fmaf chain in both passes.
// ---------------------------------------------------------------------------
__device__ __forceinline__ float dist2(const float4 a, const float4 b)
{
    const float dot = fmaf(a.x, b.x, fmaf(a.y, b.y, a.z * b.z));
    return fmaf(-2.0f, dot, a.w + b.w);
}
__device__ __forceinline__ unsigned sortkey(const float d2)
{
    unsigned u = __float_as_uint(d2);
    u ^= (unsigned)((int)u >> 31) | 0x80000000u;
    return u;
}

constexpr int CAP = 128;
constexpr int QW  = 4;     // queries per wave

__global__ __launch_bounds__(256) void knn_kernel(const float4* __restrict__ pos4,
                                                  int* __restrict__ idx_out)
{
    __shared__ unsigned long long surv[16][CAP];   // 16 KB
    __shared__ int scnt[16];

    const int tid   = threadIdx.x;
    const int w     = tid >> 6;
    const int lane  = tid & 63;
    const int qbase = blockIdx.x * 16 + w * QW;

    if (lane < QW) scnt[w * QW + lane] = 0;

    float4 qp[QW];
#pragma unroll
    for (int qi = 0; qi < QW; ++qi) qp[qi] = pos4[qbase + qi];

    float mn[QW];
#pragma unroll
    for (int qi = 0; qi < QW; ++qi) mn[qi] = 1e30f;

    // ---- pass 1: per-lane min per query ----
#pragma unroll 4
    for (int t = 0; t < N_PTS / 64; ++t) {
        const float4 p = pos4[t * 64 + lane];
#pragma unroll
        for (int qi = 0; qi < QW; ++qi)
            mn[qi] = fminf(mn[qi], dist2(qp[qi], p));
    }

    // ---- T = 16th smallest of 64 lane-mins (bitonic sort across lanes) ----
    float T[QW];
#pragma unroll
    for (int qi = 0; qi < QW; ++qi) {
        float v = mn[qi];
#pragma unroll
        for (int k = 2; k <= 64; k <<= 1)
#pragma unroll
            for (int j = k >> 1; j > 0; j >>= 1) {
                const float o = __shfl_xor(v, j);
                const bool up = ((lane & k) == 0);
                const bool lo = ((lane & j) == 0);
                v = (up == lo) ? fminf(v, o) : fmaxf(v, o);
            }
        T[qi] = __shfl(v, 15);
    }

    // ---- pass 2: collect survivors ----
#pragma unroll 2
    for (int t = 0; t < N_PTS / 64; ++t) {
        const int j = t * 64 + lane;
        const float4 p = pos4[j];
#pragma unroll
        for (int qi = 0; qi < QW; ++qi) {
            const float d = dist2(qp[qi], p);
            if (d <= T[qi]) {
                const int qs = w * QW + qi;
                const int slot = atomicAdd(&scnt[qs], 1);
                if (slot < CAP)
                    surv[qs][slot] = ((unsigned long long)sortkey(d) << 32) | (unsigned)j;
            }
        }
    }
    asm volatile("s_waitcnt lgkmcnt(0)" ::: "memory");

    // ---- exact top-16 per query ----
    for (int qi = 0; qi < QW; ++qi) {
        const int qs = w * QW + qi;
        const int n = min(scnt[qs], CAP);
        unsigned long long c0 = (lane < n) ? surv[qs][lane] : ~0ull;
        unsigned long long c1 = (lane + 64 < n) ? surv[qs][lane + 64] : ~0ull;
        for (int r = 0; r < KNN; ++r) {
            unsigned long long m = c0 < c1 ? c0 : c1;
#pragma unroll
            for (int d = 32; d >= 1; d >>= 1) {
                const unsigned long long o = __shfl_xor(m, d);
                if (o < m) m = o;
            }
            if (c0 == m) c0 = ~0ull;
            else if (c1 == m) c1 = ~0ull;
            if (lane == 0) idx_out[(qbase + qi) * KNN + r] = (int)(unsigned)(m & 0xFFFFFFFFu);
        }
    }
}

// ---------------------------------------------------------------------------
// MFMA PointNetConv (unchanged from R2).
// ---------------------------------------------------------------------------
template <int CIN, int CMID, int COUT, int WM, int WN>
__global__ __launch_bounds__(256) void conv_mfma(
    const float* __restrict__ x, const float* __restrict__ pos,
    const int* __restrict__ idx,
    const uint4* __restrict__ fA, const float* __restrict__ ba,
    const uint4* __restrict__ fB, const float* __restrict__ bb,
    float* __restrict__ out)
{
    constexpr int PB  = 8, M = 128;
    constexpr int K1  = (CIN + 3 + 31) & ~31;   // 32 or 96
    constexpr int KS1 = K1 / 32;
    constexpr int KP1 = K1 + 8;
    constexpr int KS2 = CMID / 32;
    constexpr int KP2 = CMID + 8;
    constexpr int NT  = COUT / 16;
    constexpr int NTW = NT / WN;                // 4
    constexpr int MFW = (M / 16) / WM;          // 2 or 4

    __shared__ unsigned short msg[M][KP1];
    __shared__ unsigned short hbuf[M][KP2];
    __shared__ int nbr[M];

    const int tid  = threadIdx.x;
    const int lane = tid & 63;
    const int w    = tid >> 6;
    const int wm   = w / WN, wn = w % WN;
    const int i0   = blockIdx.x * PB;

    if (tid < M) nbr[tid] = idx[i0 * KNN + tid];
    __syncthreads();

    if constexpr (CIN == 3) {
        if (tid < M) {
            const int row = tid, p = row >> 4, j = nbr[row];
            const float ax = pos[j * 3 + 0], ay = pos[j * 3 + 1], az = pos[j * 3 + 2];
            const float bx = pos[(i0 + p) * 3 + 0], by = pos[(i0 + p) * 3 + 1],
                        bz = pos[(i0 + p) * 3 + 2];
            uint4 c0;
            c0.x = pack2(ax, ay);
            c0.y = pack2(az, ax - bx);
            c0.z = pack2(ay - by, az - bz);
            c0.w = 0u;
            *reinterpret_cast<uint4*>(&msg[row][0]) = c0;
            const uint4 z = make_uint4(0, 0, 0, 0);
            *reinterpret_cast<uint4*>(&msg[row][8])  = z;
            *reinterpret_cast<uint4*>(&msg[row][16]) = z;
            *reinterpret_cast<uint4*>(&msg[row][24]) = z;
        }
    } else {
        const int row = tid >> 1, hh = tid & 1;
        const int j = nbr[row];
        const float* xr = x + j * CIN + hh * 32;
#pragma unroll
        for (int cc = 0; cc < 32; cc += 8) {
            const float4 f0 = *reinterpret_cast<const float4*>(xr + cc);
            const float4 f1 = *reinterpret_cast<const float4*>(xr + cc + 4);
            uint4 o;
            o.x = pack2(f0.x, f0.y); o.y = pack2(f0.z, f0.w);
            o.z = pack2(f1.x, f1.y); o.w = pack2(f1.z, f1.w);
            *reinterpret_cast<uint4*>(&msg[row][hh * 32 + cc]) = o;
        }
        if (hh) {
            const int p = row >> 4;
            const float rx = pos[j * 3 + 0] - pos[(i0 + p) * 3 + 0];
            const float ry = pos[j * 3 + 1] - pos[(i0 + p) * 3 + 1];
            const float rz = pos[j * 3 + 2] - pos[(i0 + p) * 3 + 2];
            uint4 c0;
            c0.x = pack2(rx, ry);
            c0.y = pack2(rz, 0.0f);
            c0.z = 0u; c0.w = 0u;
            *reinterpret_cast<uint4*>(&msg[row][64]) = c0;
            const uint4 z = make_uint4(0, 0, 0, 0);
            *reinterpret_cast<uint4*>(&msg[row][72]) = z;
            *reinterpret_cast<uint4*>(&msg[row][80]) = z;
            *reinterpret_cast<uint4*>(&msg[row][88]) = z;
        }
    }
    __syncthreads();

    {   // GEMM1: h = relu(msg @ Wa + ba)
        uint4 b1[KS1][NTW];
#pragma unroll
        for (int ks = 0; ks < KS1; ++ks)
#pragma unroll
            for (int nt = 0; nt < NTW; ++nt)
                b1[ks][nt] = fA[(ks * NT + wn * NTW + nt) * 64 + lane];

        f32x4v acc[MFW][NTW];
#pragma unroll
        for (int mf = 0; mf < MFW; ++mf)
#pragma unroll
            for (int nt = 0; nt < NTW; ++nt) acc[mf][nt] = (f32x4v)0.0f;

#pragma unroll
        for (int mf = 0; mf < MFW; ++mf) {
            bf16x8 a[KS1];
#pragma unroll
            for (int ks = 0; ks < KS1; ++ks)
                a[ks] = *reinterpret_cast<const bf16x8*>(
                    &msg[(wm * MFW + mf) * 16 + (lane & 15)][ks * 32 + (lane >> 4) * 8]);
#pragma unroll
            for (int nt = 0; nt < NTW; ++nt)
#pragma unroll
                for (int ks = 0; ks < KS1; ++ks)
                    acc[mf][nt] = __builtin_amdgcn_mfma_f32_16x16x32_bf16(
                        a[ks], __builtin_bit_cast(bf16x8, b1[ks][nt]), acc[mf][nt], 0, 0, 0);
        }

        float bav[NTW];
#pragma unroll
        for (int nt = 0; nt < NTW; ++nt) bav[nt] = ba[(wn * NTW + nt) * 16 + (lane & 15)];

#pragma unroll
        for (int mf = 0; mf < MFW; ++mf)
#pragma unroll
            for (int nt = 0; nt < NTW; ++nt)
#pragma unroll
                for (int r = 0; r < 4; ++r) {
                    const float v = fmaxf(acc[mf][nt][r] + bav[nt], 0.0f);
                    hbuf[(wm * MFW + mf) * 16 + (lane >> 4) * 4 + r]
                        [(wn * NTW + nt) * 16 + (lane & 15)] = f2bf(v);
                }
    }
    __syncthreads();

    {   // GEMM2: out = relu(max_k(htile @ Wb) + bb)
        uint4 b2[KS2][NTW];
#pragma unroll
        for (int ks = 0; ks < KS2; ++ks)
#pragma unroll
            for (int nt = 0; nt < NTW; ++nt)
                b2[ks][nt] = fB[(ks * NT + wn * NTW + nt) * 64 + lane];

        f32x4v acc[MFW][NTW];
#pragma unroll
        for (int mf = 0; mf < MFW; ++mf)
#pragma unroll
            for (int nt = 0; nt < NTW; ++nt) acc[mf][nt] = (f32x4v)0.0f;

#pragma unroll
        for (int mf = 0; mf < MFW; ++mf) {
            bf16x8 a[KS2];
#pragma unroll
            for (int ks = 0; ks < KS2; ++ks)
                a[ks] = *reinterpret_cast<const bf16x8*>(
                    &hbuf[(wm * MFW + mf) * 16 + (lane & 15)][ks * 32 + (lane >> 4) * 8]);
#pragma unroll
            for (int nt = 0; nt < NTW; ++nt)
#pragma unroll
                for (int ks = 0; ks < KS2; ++ks)
                    acc[mf][nt] = __builtin_amdgcn_mfma_f32_16x16x32_bf16(
                        a[ks], __builtin_bit_cast(bf16x8, b2[ks][nt]), acc[mf][nt], 0, 0, 0);
        }

        float bbv[NTW];
#pragma unroll
        for (int nt = 0; nt < NTW; ++nt) bbv[nt] = bb[(wn * NTW + nt) * 16 + (lane & 15)];

#pragma unroll
        for (int mf = 0; mf < MFW; ++mf)
#pragma unroll
            for (int nt = 0; nt < NTW; ++nt) {
                const f32x4v t = acc[mf][nt];
                float m0 = fmaxf(fmaxf(t[0], t[1]), fmaxf(t[2], t[3]));
                m0 = fmaxf(m0, __shfl_xor(m0, 16));
                m0 = fmaxf(m0, __shfl_xor(m0, 32));
                const float v = fmaxf(m0 + bbv[nt], 0.0f);
                if (lane < 16)
                    out[(i0 + wm * MFW + mf) * COUT + (wn * NTW + nt) * 16 + lane] = v;
            }
    }
}

extern "C" void kernel_launch(void* const* d_in, const int* in_sizes, int n_in,
                              void* d_out, int out_size, void* d_ws, size_t ws_size,
                              hipStream_t stream)
{
    const float* pos = (const float*)d_in[0];
    const float* W1a = (const float*)d_in[1];
    const float* b1a = (const float*)d_in[2];
    const float* W1b = (const float*)d_in[3];
    const float* b1b = (const float*)d_in[4];
    const float* W2a = (const float*)d_in[5];
    const float* b2a = (const float*)d_in[6];
    const float* W2b = (const float*)d_in[7];
    const float* b2b = (const float*)d_in[8];
    const float* W3a = (const float*)d_in[9];
    const float* b3a = (const float*)d_in[10];
    const float* W3b = (const float*)d_in[11];
    const float* b3b = (const float*)d_in[12];

    float* out = (float*)d_out;
    float* h1 = out;                        // 8192 x 64
    float* h2 = out + N_PTS * 64;           // 8192 x 64
    float* h3 = out + N_PTS * 128;          // 8192 x 128

    int*   idx     = (int*)d_ws;                                   // 512 KB
    uint4* wsFrags = (uint4*)((char*)d_ws + N_PTS * KNN * 4);      // 88 KB

    // pos4 scratch in h3 region (dead before conv3 writes h3)
    float4* pos4 = (float4*)h3;

    prep_weights<<<88, 64, 0, stream>>>(W1a, W1b, W2a, W2b, W3a, W3b, wsFrags);
    prep_kernel<<<N_PTS / 256, 256, 0, stream>>>(pos, pos4);
    knn_kernel<<<N_PTS / 16, 256, 0, stream>>>(pos4, idx);

    const uint4* fW1a = wsFrags + 0 * 64;
    const uint4* fW1b = wsFrags + 4 * 64;
    const uint4* fW2a = wsFrags + 12 * 64;
    const uint4* fW2b = wsFrags + 24 * 64;
    const uint4* fW3a = wsFrags + 32 * 64;
    const uint4* fW3b = wsFrags + 56 * 64;

    conv_mfma<3, 64, 64, 4, 1><<<N_PTS / 8, 256, 0, stream>>>(
        pos, pos, idx, fW1a, b1a, fW1b, b1b, h1);
    conv_mfma<64, 64, 64, 4, 1><<<N_PTS / 8, 256, 0, stream>>>(
        h1, pos, idx, fW2a, b2a, fW2b, b2b, h2);
    conv_mfma<64, 128, 128, 2, 2><<<N_PTS / 8, 256, 0, stream>>>(
        h2, pos, idx, fW3a, b3a, fW3b, b3b, h3);
}

// Round 5
// 111.955 us; speedup vs baseline: 5.4881x; 1.0682x over previous
//
#include <hip/hip_runtime.h>
#include <math.h>

#define N_PTS 8192
#define KNN 16

typedef __attribute__((ext_vector_type(8))) short bf16x8;
typedef __attribute__((ext_vector_type(4))) float f32x4v;

__device__ __forceinline__ unsigned short f2bf(float f)
{
    unsigned u = __float_as_uint(f);
    u = u + 0x7fffu + ((u >> 16) & 1u);       // round-to-nearest-even
    return (unsigned short)(u >> 16);
}
__device__ __forceinline__ unsigned pack2(float a, float b)
{
    return (unsigned)f2bf(a) | ((unsigned)f2bf(b) << 16);
}

// ---------------------------------------------------------------------------
// pos4 prep
// ---------------------------------------------------------------------------
__global__ __launch_bounds__(256) void prep_kernel(const float* __restrict__ pos,
                                                   float4* __restrict__ pos4)
{
    const int i = blockIdx.x * 256 + threadIdx.x;
    const float x = pos[i * 3 + 0];
    const float y = pos[i * 3 + 1];
    const float z = pos[i * 3 + 2];
    pos4[i] = make_float4(x, y, z, fmaf(x, x, fmaf(y, y, z * z)));
}

// ---------------------------------------------------------------------------
// Weight prep: pack W (K x N, f32, row-major) into MFMA B-fragment layout.
// ---------------------------------------------------------------------------
__global__ __launch_bounds__(64) void prep_weights(
    const float* __restrict__ w1a, const float* __restrict__ w1b,
    const float* __restrict__ w2a, const float* __restrict__ w2b,
    const float* __restrict__ w3a, const float* __restrict__ w3b,
    uint4* __restrict__ dst)
{
    const float* Ws[6] = {w1a, w1b, w2a, w2b, w3a, w3b};
    const int Kd[6] = {6, 64, 67, 64, 67, 128};
    const int Nd[6] = {64, 64, 64, 64, 128, 128};
    const int start[7] = {0, 4, 12, 24, 32, 56, 88};

    const int b = blockIdx.x;
    int m = 0;
    while (b >= start[m + 1]) ++m;
    const int f  = b - start[m];
    const int NT = Nd[m] / 16;
    const int ks = f / NT, nt = f % NT;

    const int lane = threadIdx.x;
    const int c  = nt * 16 + (lane & 15);
    const int k0 = ks * 32 + (lane >> 4) * 8;
    const int K = Kd[m], N = Nd[m];
    const float* W = Ws[m];

    float v[8];
#pragma unroll
    for (int j = 0; j < 8; ++j) {
        const int kk = k0 + j;
        v[j] = (kk < K) ? W[kk * N + c] : 0.0f;
    }
    uint4 o;
    o.x = pack2(v[0], v[1]); o.y = pack2(v[2], v[3]);
    o.z = pack2(v[4], v[5]); o.w = pack2(v[6], v[7]);
    dst[b * 64 + lane] = o;
}

// ---------------------------------------------------------------------------
// kNN threshold-select, wave-split edition. Block = 16 queries, 4 waves.
// Wave w scans candidate chunk [w*2048, (w+1)*2048) for ALL 16 queries
// (~82 VALU per 16B load -> latency hidden by ILP). Metric: s = |pj|^2 -
// 2*dot(qi,pj); d2 = |qi|^2 + s is monotone in s per query, so selection and
// ranking by s are exact. Lane partitions (column j%64) are identical to the
// per-wave-full-scan version: combined lane-mins across waves give the same
// threshold T (16th smallest of 64 partition mins >= true 16th distance).
// Pass 2 collects survivors s <= T into a block-shared list; exact top-16 by
// (sortkey(s)||idx) 16-round wave min, 4 queries merged per wave.
// ---------------------------------------------------------------------------
__device__ __forceinline__ unsigned sortkey(const float d2)
{
    unsigned u = __float_as_uint(d2);
    u ^= (unsigned)((int)u >> 31) | 0x80000000u;
    return u;
}

constexpr int CAP = 128;
constexpr int QB  = 16;     // queries per block

__global__ __launch_bounds__(256) void knn_kernel(const float4* __restrict__ pos4,
                                                  int* __restrict__ idx_out)
{
    __shared__ float mins[QB][4][64];              // 16 KB
    __shared__ float Ts[QB];
    __shared__ unsigned long long surv[QB][CAP];   // 16 KB
    __shared__ int scnt[QB];

    const int tid   = threadIdx.x;
    const int w     = tid >> 6;
    const int lane  = tid & 63;
    const int qbase = blockIdx.x * QB;
    const int cbase = w * (N_PTS / 4);

    if (tid < QB) scnt[tid] = 0;

    float qx[QB], qy[QB], qz[QB];
#pragma unroll
    for (int qi = 0; qi < QB; ++qi) {
        const float4 qp = pos4[qbase + qi];
        qx[qi] = qp.x; qy[qi] = qp.y; qz[qi] = qp.z;
    }

    float mn[QB];
#pragma unroll
    for (int qi = 0; qi < QB; ++qi) mn[qi] = 1e30f;

    // ---- pass 1: per-lane min of s over this wave's chunk, all 16 queries ----
#pragma unroll 2
    for (int t = 0; t < N_PTS / 4 / 64; ++t) {
        const float4 p = pos4[cbase + t * 64 + lane];
#pragma unroll
        for (int qi = 0; qi < QB; ++qi) {
            const float dot = fmaf(qx[qi], p.x, fmaf(qy[qi], p.y, qz[qi] * p.z));
            mn[qi] = fminf(mn[qi], fmaf(-2.0f, dot, p.w));
        }
    }
#pragma unroll
    for (int qi = 0; qi < QB; ++qi) mins[qi][w][lane] = mn[qi];
    __syncthreads();

    // ---- T per query: wave w sorts queries 4w..4w+3 ----
#pragma unroll
    for (int k = 0; k < 4; ++k) {
        const int q = w * 4 + k;
        float v = fminf(fminf(mins[q][0][lane], mins[q][1][lane]),
                        fminf(mins[q][2][lane], mins[q][3][lane]));
#pragma unroll
        for (int kk = 2; kk <= 64; kk <<= 1)
#pragma unroll
            for (int j = kk >> 1; j > 0; j >>= 1) {
                const float o = __shfl_xor(v, j);
                const bool up = ((lane & kk) == 0);
                const bool lo = ((lane & j) == 0);
                v = (up == lo) ? fminf(v, o) : fmaxf(v, o);
            }
        if (lane == 15) Ts[q] = v;
    }
    __syncthreads();

    float T[QB];
#pragma unroll
    for (int qi = 0; qi < QB; ++qi) T[qi] = Ts[qi];

    // ---- pass 2: collect survivors from this wave's chunk ----
#pragma unroll 2
    for (int t = 0; t < N_PTS / 4 / 64; ++t) {
        const int j = cbase + t * 64 + lane;
        const float4 p = pos4[j];
#pragma unroll
        for (int qi = 0; qi < QB; ++qi) {
            const float dot = fmaf(qx[qi], p.x, fmaf(qy[qi], p.y, qz[qi] * p.z));
            const float s = fmaf(-2.0f, dot, p.w);
            if (s <= T[qi]) {
                const int slot = atomicAdd(&scnt[qi], 1);
                if (slot < CAP)
                    surv[qi][slot] = ((unsigned long long)sortkey(s) << 32) | (unsigned)j;
            }
        }
    }
    __syncthreads();

    // ---- exact top-16: wave w merges queries 4w..4w+3 ----
    for (int k = 0; k < 4; ++k) {
        const int q = w * 4 + k;
        const int n = min(scnt[q], CAP);
        unsigned long long c0 = (lane < n) ? surv[q][lane] : ~0ull;
        unsigned long long c1 = (lane + 64 < n) ? surv[q][lane + 64] : ~0ull;
        for (int r = 0; r < KNN; ++r) {
            unsigned long long m = c0 < c1 ? c0 : c1;
#pragma unroll
            for (int d = 32; d >= 1; d >>= 1) {
                const unsigned long long o = __shfl_xor(m, d);
                if (o < m) m = o;
            }
            if (c0 == m) c0 = ~0ull;
            else if (c1 == m) c1 = ~0ull;
            if (lane == 0) idx_out[(qbase + q) * KNN + r] = (int)(unsigned)(m & 0xFFFFFFFFu);
        }
    }
}

// ---------------------------------------------------------------------------
// MFMA PointNetConv (unchanged from R2).
// ---------------------------------------------------------------------------
template <int CIN, int CMID, int COUT, int WM, int WN>
__global__ __launch_bounds__(256) void conv_mfma(
    const float* __restrict__ x, const float* __restrict__ pos,
    const int* __restrict__ idx,
    const uint4* __restrict__ fA, const float* __restrict__ ba,
    const uint4* __restrict__ fB, const float* __restrict__ bb,
    float* __restrict__ out)
{
    constexpr int PB  = 8, M = 128;
    constexpr int K1  = (CIN + 3 + 31) & ~31;   // 32 or 96
    constexpr int KS1 = K1 / 32;
    constexpr int KP1 = K1 + 8;
    constexpr int KS2 = CMID / 32;
    constexpr int KP2 = CMID + 8;
    constexpr int NT  = COUT / 16;
    constexpr int NTW = NT / WN;                // 4
    constexpr int MFW = (M / 16) / WM;          // 2 or 4

    __shared__ unsigned short msg[M][KP1];
    __shared__ unsigned short hbuf[M][KP2];
    __shared__ int nbr[M];

    const int tid  = threadIdx.x;
    const int lane = tid & 63;
    const int w    = tid >> 6;
    const int wm   = w / WN, wn = w % WN;
    const int i0   = blockIdx.x * PB;

    if (tid < M) nbr[tid] = idx[i0 * KNN + tid];
    __syncthreads();

    if constexpr (CIN == 3) {
        if (tid < M) {
            const int row = tid, p = row >> 4, j = nbr[row];
            const float ax = pos[j * 3 + 0], ay = pos[j * 3 + 1], az = pos[j * 3 + 2];
            const float bx = pos[(i0 + p) * 3 + 0], by = pos[(i0 + p) * 3 + 1],
                        bz = pos[(i0 + p) * 3 + 2];
            uint4 c0;
            c0.x = pack2(ax, ay);
            c0.y = pack2(az, ax - bx);
            c0.z = pack2(ay - by, az - bz);
            c0.w = 0u;
            *reinterpret_cast<uint4*>(&msg[row][0]) = c0;
            const uint4 z = make_uint4(0, 0, 0, 0);
            *reinterpret_cast<uint4*>(&msg[row][8])  = z;
            *reinterpret_cast<uint4*>(&msg[row][16]) = z;
            *reinterpret_cast<uint4*>(&msg[row][24]) = z;
        }
    } else {
        const int row = tid >> 1, hh = tid & 1;
        const int j = nbr[row];
        const float* xr = x + j * CIN + hh * 32;
#pragma unroll
        for (int cc = 0; cc < 32; cc += 8) {
            const float4 f0 = *reinterpret_cast<const float4*>(xr + cc);
            const float4 f1 = *reinterpret_cast<const float4*>(xr + cc + 4);
            uint4 o;
            o.x = pack2(f0.x, f0.y); o.y = pack2(f0.z, f0.w);
            o.z = pack2(f1.x, f1.y); o.w = pack2(f1.z, f1.w);
            *reinterpret_cast<uint4*>(&msg[row][hh * 32 + cc]) = o;
        }
        if (hh) {
            const int p = row >> 4;
            const float rx = pos[j * 3 + 0] - pos[(i0 + p) * 3 + 0];
            const float ry = pos[j * 3 + 1] - pos[(i0 + p) * 3 + 1];
            const float rz = pos[j * 3 + 2] - pos[(i0 + p) * 3 + 2];
            uint4 c0;
            c0.x = pack2(rx, ry);
            c0.y = pack2(rz, 0.0f);
            c0.z = 0u; c0.w = 0u;
            *reinterpret_cast<uint4*>(&msg[row][64]) = c0;
            const uint4 z = make_uint4(0, 0, 0, 0);
            *reinterpret_cast<uint4*>(&msg[row][72]) = z;
            *reinterpret_cast<uint4*>(&msg[row][80]) = z;
            *reinterpret_cast<uint4*>(&msg[row][88]) = z;
        }
    }
    __syncthreads();

    {   // GEMM1: h = relu(msg @ Wa + ba)
        uint4 b1[KS1][NTW];
#pragma unroll
        for (int ks = 0; ks < KS1; ++ks)
#pragma unroll
            for (int nt = 0; nt < NTW; ++nt)
                b1[ks][nt] = fA[(ks * NT + wn * NTW + nt) * 64 + lane];

        f32x4v acc[MFW][NTW];
#pragma unroll
        for (int mf = 0; mf < MFW; ++mf)
#pragma unroll
            for (int nt = 0; nt < NTW; ++nt) acc[mf][nt] = (f32x4v)0.0f;

#pragma unroll
        for (int mf = 0; mf < MFW; ++mf) {
            bf16x8 a[KS1];
#pragma unroll
            for (int ks = 0; ks < KS1; ++ks)
                a[ks] = *reinterpret_cast<const bf16x8*>(
                    &msg[(wm * MFW + mf) * 16 + (lane & 15)][ks * 32 + (lane >> 4) * 8]);
#pragma unroll
            for (int nt = 0; nt < NTW; ++nt)
#pragma unroll
                for (int ks = 0; ks < KS1; ++ks)
                    acc[mf][nt] = __builtin_amdgcn_mfma_f32_16x16x32_bf16(
                        a[ks], __builtin_bit_cast(bf16x8, b1[ks][nt]), acc[mf][nt], 0, 0, 0);
        }

        float bav[NTW];
#pragma unroll
        for (int nt = 0; nt < NTW; ++nt) bav[nt] = ba[(wn * NTW + nt) * 16 + (lane & 15)];

#pragma unroll
        for (int mf = 0; mf < MFW; ++mf)
#pragma unroll
            for (int nt = 0; nt < NTW; ++nt)
#pragma unroll
                for (int r = 0; r < 4; ++r) {
                    const float v = fmaxf(acc[mf][nt][r] + bav[nt], 0.0f);
                    hbuf[(wm * MFW + mf) * 16 + (lane >> 4) * 4 + r]
                        [(wn * NTW + nt) * 16 + (lane & 15)] = f2bf(v);
                }
    }
    __syncthreads();

    {   // GEMM2: out = relu(max_k(htile @ Wb) + bb)
        uint4 b2[KS2][NTW];
#pragma unroll
        for (int ks = 0; ks < KS2; ++ks)
#pragma unroll
            for (int nt = 0; nt < NTW; ++nt)
                b2[ks][nt] = fB[(ks * NT + wn * NTW + nt) * 64 + lane];

        f32x4v acc[MFW][NTW];
#pragma unroll
        for (int mf = 0; mf < MFW; ++mf)
#pragma unroll
            for (int nt = 0; nt < NTW; ++nt) acc[mf][nt] = (f32x4v)0.0f;

#pragma unroll
        for (int mf = 0; mf < MFW; ++mf) {
            bf16x8 a[KS2];
#pragma unroll
            for (int ks = 0; ks < KS2; ++ks)
                a[ks] = *reinterpret_cast<const bf16x8*>(
                    &hbuf[(wm * MFW + mf) * 16 + (lane & 15)][ks * 32 + (lane >> 4) * 8]);
#pragma unroll
            for (int nt = 0; nt < NTW; ++nt)
#pragma unroll
                for (int ks = 0; ks < KS2; ++ks)
                    acc[mf][nt] = __builtin_amdgcn_mfma_f32_16x16x32_bf16(
                        a[ks], __builtin_bit_cast(bf16x8, b2[ks][nt]), acc[mf][nt], 0, 0, 0);
        }

        float bbv[NTW];
#pragma unroll
        for (int nt = 0; nt < NTW; ++nt) bbv[nt] = bb[(wn * NTW + nt) * 16 + (lane & 15)];

#pragma unroll
        for (int mf = 0; mf < MFW; ++mf)
#pragma unroll
            for (int nt = 0; nt < NTW; ++nt) {
                const f32x4v t = acc[mf][nt];
                float m0 = fmaxf(fmaxf(t[0], t[1]), fmaxf(t[2], t[3]));
                m0 = fmaxf(m0, __shfl_xor(m0, 16));
                m0 = fmaxf(m0, __shfl_xor(m0, 32));
                const float v = fmaxf(m0 + bbv[nt], 0.0f);
                if (lane < 16)
                    out[(i0 + wm * MFW + mf) * COUT + (wn * NTW + nt) * 16 + lane] = v;
            }
    }
}

extern "C" void kernel_launch(void* const* d_in, const int* in_sizes, int n_in,
                              void* d_out, int out_size, void* d_ws, size_t ws_size,
                              hipStream_t stream)
{
    const float* pos = (const float*)d_in[0];
    const float* W1a = (const float*)d_in[1];
    const float* b1a = (const float*)d_in[2];
    const float* W1b = (const float*)d_in[3];
    const float* b1b = (const float*)d_in[4];
    const float* W2a = (const float*)d_in[5];
    const float* b2a = (const float*)d_in[6];
    const float* W2b = (const float*)d_in[7];
    const float* b2b = (const float*)d_in[8];
    const float* W3a = (const float*)d_in[9];
    const float* b3a = (const float*)d_in[10];
    const float* W3b = (const float*)d_in[11];
    const float* b3b = (const float*)d_in[12];

    float* out = (float*)d_out;
    float* h1 = out;                        // 8192 x 64
    float* h2 = out + N_PTS * 64;           // 8192 x 64
    float* h3 = out + N_PTS * 128;          // 8192 x 128

    int*   idx     = (int*)d_ws;                                   // 512 KB
    uint4* wsFrags = (uint4*)((char*)d_ws + N_PTS * KNN * 4);      // 88 KB

    // pos4 scratch in h3 region (dead before conv3 writes h3)
    float4* pos4 = (float4*)h3;

    prep_weights<<<88, 64, 0, stream>>>(W1a, W1b, W2a, W2b, W3a, W3b, wsFrags);
    prep_kernel<<<N_PTS / 256, 256, 0, stream>>>(pos, pos4);
    knn_kernel<<<N_PTS / QB, 256, 0, stream>>>(pos4, idx);

    const uint4* fW1a = wsFrags + 0 * 64;
    const uint4* fW1b = wsFrags + 4 * 64;
    const uint4* fW2a = wsFrags + 12 * 64;
    const uint4* fW2b = wsFrags + 24 * 64;
    const uint4* fW3a = wsFrags + 32 * 64;
    const uint4* fW3b = wsFrags + 56 * 64;

    conv_mfma<3, 64, 64, 4, 1><<<N_PTS / 8, 256, 0, stream>>>(
        pos, pos, idx, fW1a, b1a, fW1b, b1b, h1);
    conv_mfma<64, 64, 64, 4, 1><<<N_PTS / 8, 256, 0, stream>>>(
        h1, pos, idx, fW2a, b2a, fW2b, b2b, h2);
    conv_mfma<64, 128, 128, 2, 2><<<N_PTS / 8, 256, 0, stream>>>(
        h2, pos, idx, fW3a, b3a, fW3b, b3b, h3);
}

// Round 6
// 78.549 us; speedup vs baseline: 7.8221x; 1.4253x over previous
//
#include <hip/hip_runtime.h>
#include <math.h>

#define N_PTS 8192
#define KNN 16

typedef __attribute__((ext_vector_type(8))) short bf16x8;
typedef __attribute__((ext_vector_type(4))) float f32x4v;

__device__ __forceinline__ unsigned short f2bf(float f)
{
    unsigned u = __float_as_uint(f);
    u = u + 0x7fffu + ((u >> 16) & 1u);       // round-to-nearest-even
    return (unsigned short)(u >> 16);
}
__device__ __forceinline__ unsigned pack2(float a, float b)
{
    return (unsigned)f2bf(a) | ((unsigned)f2bf(b) << 16);
}
__device__ __forceinline__ float rfl(float x)   // force to SGPR (block-uniform values)
{
    return __int_as_float(__builtin_amdgcn_readfirstlane(__float_as_int(x)));
}

// ---------------------------------------------------------------------------
// pos4 prep: (x, y, z, |p|^2)
// ---------------------------------------------------------------------------
__global__ __launch_bounds__(256) void prep_kernel(const float* __restrict__ pos,
                                                   float4* __restrict__ pos4)
{
    const int i = blockIdx.x * 256 + threadIdx.x;
    const float x = pos[i * 3 + 0];
    const float y = pos[i * 3 + 1];
    const float z = pos[i * 3 + 2];
    pos4[i] = make_float4(x, y, z, fmaf(x, x, fmaf(y, y, z * z)));
}

// ---------------------------------------------------------------------------
// Weight prep: pack W (K x N, f32, row-major) into MFMA B-fragment layout.
// ---------------------------------------------------------------------------
__global__ __launch_bounds__(64) void prep_weights(
    const float* __restrict__ w1a, const float* __restrict__ w1b,
    const float* __restrict__ w2a, const float* __restrict__ w2b,
    const float* __restrict__ w3a, const float* __restrict__ w3b,
    uint4* __restrict__ dst)
{
    const float* Ws[6] = {w1a, w1b, w2a, w2b, w3a, w3b};
    const int Kd[6] = {6, 64, 67, 64, 67, 128};
    const int Nd[6] = {64, 64, 64, 64, 128, 128};
    const int start[7] = {0, 4, 12, 24, 32, 56, 88};

    const int b = blockIdx.x;
    int m = 0;
    while (b >= start[m + 1]) ++m;
    const int f  = b - start[m];
    const int NT = Nd[m] / 16;
    const int ks = f / NT, nt = f % NT;

    const int lane = threadIdx.x;
    const int c  = nt * 16 + (lane & 15);
    const int k0 = ks * 32 + (lane >> 4) * 8;
    const int K = Kd[m], N = Nd[m];
    const float* W = Ws[m];

    float v[8];
#pragma unroll
    for (int j = 0; j < 8; ++j) {
        const int kk = k0 + j;
        v[j] = (kk < K) ? W[kk * N + c] : 0.0f;
    }
    uint4 o;
    o.x = pack2(v[0], v[1]); o.y = pack2(v[2], v[3]);
    o.z = pack2(v[4], v[5]); o.w = pack2(v[6], v[7]);
    dst[b * 64 + lane] = o;
}

// ---------------------------------------------------------------------------
// kNN threshold-select, SGPR-query edition. Block = 8 queries, 4 waves; wave w
// scans candidate chunk [w*2048, (w+1)*2048) for all 8 queries. Query coords
// pre-scaled by -2 and held in SGPRs (readfirstlane) -> inner body is
// 3 fma + 1 min per (q,cand), zero spills. Metric s = |p|^2 - 2 q.p (d2 =
// |q|^2 + s monotone in s). T = 16th smallest of 64 combined lane-partition
// mins (bitonic): >= true 16th distance since the 16 smallest lane-mins are
// distinct points. Pass 2 collects s <= T (exp ~20, CAP=128); exact top-16 by
// LDS rank-select on unique keys (sortkey(s)<<32 | j), ties by lowest index.
// ---------------------------------------------------------------------------
__device__ __forceinline__ unsigned sortkey(const float d2)
{
    unsigned u = __float_as_uint(d2);
    u ^= (unsigned)((int)u >> 31) | 0x80000000u;
    return u;
}

constexpr int CAP = 128;
constexpr int QB  = 8;      // queries per block
constexpr int QW  = QB / 4; // queries finalized per wave

__global__ __launch_bounds__(256) void knn_kernel(const float4* __restrict__ pos4,
                                                  int* __restrict__ idx_out)
{
    __shared__ float mins[QB][4][64];              // 8 KB
    __shared__ float Ts[QB];
    __shared__ unsigned long long surv[QB][CAP];   // 8 KB
    __shared__ int scnt[QB];

    const int tid   = threadIdx.x;
    const int w     = tid >> 6;
    const int lane  = tid & 63;
    const int qbase = blockIdx.x * QB;
    const int cbase = w * (N_PTS / 4);

    if (tid < QB) scnt[tid] = 0;

    float qx[QB], qy[QB], qz[QB];
#pragma unroll
    for (int qi = 0; qi < QB; ++qi) {
        const float4 qp = pos4[qbase + qi];
        qx[qi] = rfl(-2.0f * qp.x);
        qy[qi] = rfl(-2.0f * qp.y);
        qz[qi] = rfl(-2.0f * qp.z);
    }

    float mn[QB];
#pragma unroll
    for (int qi = 0; qi < QB; ++qi) mn[qi] = 1e30f;

    // ---- pass 1: per-lane min of s over this wave's chunk ----
#pragma unroll 4
    for (int t = 0; t < N_PTS / 4 / 64; ++t) {
        const float4 p = pos4[cbase + t * 64 + lane];
#pragma unroll
        for (int qi = 0; qi < QB; ++qi) {
            const float s = fmaf(qx[qi], p.x, fmaf(qy[qi], p.y, fmaf(qz[qi], p.z, p.w)));
            mn[qi] = fminf(mn[qi], s);
        }
    }
#pragma unroll
    for (int qi = 0; qi < QB; ++qi) mins[qi][w][lane] = mn[qi];
    __syncthreads();

    // ---- T per query: wave w sorts queries w*QW..w*QW+QW-1 (bitonic) ----
#pragma unroll
    for (int k = 0; k < QW; ++k) {
        const int q = w * QW + k;
        float v = fminf(fminf(mins[q][0][lane], mins[q][1][lane]),
                        fminf(mins[q][2][lane], mins[q][3][lane]));
#pragma unroll
        for (int kk = 2; kk <= 64; kk <<= 1)
#pragma unroll
            for (int j = kk >> 1; j > 0; j >>= 1) {
                const float o = __shfl_xor(v, j);
                const bool up = ((lane & kk) == 0);
                const bool lo = ((lane & j) == 0);
                v = (up == lo) ? fminf(v, o) : fmaxf(v, o);
            }
        if (lane == 15) Ts[q] = v;
    }
    __syncthreads();

    float T[QB];
#pragma unroll
    for (int qi = 0; qi < QB; ++qi) T[qi] = rfl(Ts[qi]);

    // ---- pass 2: collect survivors from this wave's chunk ----
#pragma unroll 4
    for (int t = 0; t < N_PTS / 4 / 64; ++t) {
        const int j = cbase + t * 64 + lane;
        const float4 p = pos4[j];
#pragma unroll
        for (int qi = 0; qi < QB; ++qi) {
            const float s = fmaf(qx[qi], p.x, fmaf(qy[qi], p.y, fmaf(qz[qi], p.z, p.w)));
            if (s <= T[qi]) {
                const int slot = atomicAdd(&scnt[qi], 1);
                if (slot < CAP)
                    surv[qi][slot] = ((unsigned long long)sortkey(s) << 32) | (unsigned)j;
            }
        }
    }
    __syncthreads();

    // ---- exact top-16 by rank-select: rank = #{key < mine} (keys unique) ----
    for (int k = 0; k < QW; ++k) {
        const int q = w * QW + k;
        const int n = min(scnt[q], CAP);
        const unsigned long long k0 = (lane < n) ? surv[q][lane] : ~0ull;
        const unsigned long long k1 = (lane + 64 < n) ? surv[q][lane + 64] : ~0ull;
        int r0 = 0, r1 = 0;
        for (int e = 0; e < n; ++e) {
            const unsigned long long ke = surv[q][e];   // LDS broadcast read
            r0 += (ke < k0) ? 1 : 0;
            r1 += (ke < k1) ? 1 : 0;
        }
        if (lane < n && r0 < KNN)
            idx_out[(qbase + q) * KNN + r0] = (int)(unsigned)(k0 & 0xFFFFFFFFu);
        if (lane + 64 < n && r1 < KNN)
            idx_out[(qbase + q) * KNN + r1] = (int)(unsigned)(k1 & 0xFFFFFFFFu);
    }
}

// ---------------------------------------------------------------------------
// MFMA PointNetConv (unchanged from R2).
// ---------------------------------------------------------------------------
template <int CIN, int CMID, int COUT, int WM, int WN>
__global__ __launch_bounds__(256) void conv_mfma(
    const float* __restrict__ x, const float* __restrict__ pos,
    const int* __restrict__ idx,
    const uint4* __restrict__ fA, const float* __restrict__ ba,
    const uint4* __restrict__ fB, const float* __restrict__ bb,
    float* __restrict__ out)
{
    constexpr int PB  = 8, M = 128;
    constexpr int K1  = (CIN + 3 + 31) & ~31;   // 32 or 96
    constexpr int KS1 = K1 / 32;
    constexpr int KP1 = K1 + 8;
    constexpr int KS2 = CMID / 32;
    constexpr int KP2 = CMID + 8;
    constexpr int NT  = COUT / 16;
    constexpr int NTW = NT / WN;                // 4
    constexpr int MFW = (M / 16) / WM;          // 2 or 4

    __shared__ unsigned short msg[M][KP1];
    __shared__ unsigned short hbuf[M][KP2];
    __shared__ int nbr[M];

    const int tid  = threadIdx.x;
    const int lane = tid & 63;
    const int w    = tid >> 6;
    const int wm   = w / WN, wn = w % WN;
    const int i0   = blockIdx.x * PB;

    if (tid < M) nbr[tid] = idx[i0 * KNN + tid];
    __syncthreads();

    if constexpr (CIN == 3) {
        if (tid < M) {
            const int row = tid, p = row >> 4, j = nbr[row];
            const float ax = pos[j * 3 + 0], ay = pos[j * 3 + 1], az = pos[j * 3 + 2];
            const float bx = pos[(i0 + p) * 3 + 0], by = pos[(i0 + p) * 3 + 1],
                        bz = pos[(i0 + p) * 3 + 2];
            uint4 c0;
            c0.x = pack2(ax, ay);
            c0.y = pack2(az, ax - bx);
            c0.z = pack2(ay - by, az - bz);
            c0.w = 0u;
            *reinterpret_cast<uint4*>(&msg[row][0]) = c0;
            const uint4 z = make_uint4(0, 0, 0, 0);
            *reinterpret_cast<uint4*>(&msg[row][8])  = z;
            *reinterpret_cast<uint4*>(&msg[row][16]) = z;
            *reinterpret_cast<uint4*>(&msg[row][24]) = z;
        }
    } else {
        const int row = tid >> 1, hh = tid & 1;
        const int j = nbr[row];
        const float* xr = x + j * CIN + hh * 32;
#pragma unroll
        for (int cc = 0; cc < 32; cc += 8) {
            const float4 f0 = *reinterpret_cast<const float4*>(xr + cc);
            const float4 f1 = *reinterpret_cast<const float4*>(xr + cc + 4);
            uint4 o;
            o.x = pack2(f0.x, f0.y); o.y = pack2(f0.z, f0.w);
            o.z = pack2(f1.x, f1.y); o.w = pack2(f1.z, f1.w);
            *reinterpret_cast<uint4*>(&msg[row][hh * 32 + cc]) = o;
        }
        if (hh) {
            const int p = row >> 4;
            const float rx = pos[j * 3 + 0] - pos[(i0 + p) * 3 + 0];
            const float ry = pos[j * 3 + 1] - pos[(i0 + p) * 3 + 1];
            const float rz = pos[j * 3 + 2] - pos[(i0 + p) * 3 + 2];
            uint4 c0;
            c0.x = pack2(rx, ry);
            c0.y = pack2(rz, 0.0f);
            c0.z = 0u; c0.w = 0u;
            *reinterpret_cast<uint4*>(&msg[row][64]) = c0;
            const uint4 z = make_uint4(0, 0, 0, 0);
            *reinterpret_cast<uint4*>(&msg[row][72]) = z;
            *reinterpret_cast<uint4*>(&msg[row][80]) = z;
            *reinterpret_cast<uint4*>(&msg[row][88]) = z;
        }
    }
    __syncthreads();

    {   // GEMM1: h = relu(msg @ Wa + ba)
        uint4 b1[KS1][NTW];
#pragma unroll
        for (int ks = 0; ks < KS1; ++ks)
#pragma unroll
            for (int nt = 0; nt < NTW; ++nt)
                b1[ks][nt] = fA[(ks * NT + wn * NTW + nt) * 64 + lane];

        f32x4v acc[MFW][NTW];
#pragma unroll
        for (int mf = 0; mf < MFW; ++mf)
#pragma unroll
            for (int nt = 0; nt < NTW; ++nt) acc[mf][nt] = (f32x4v)0.0f;

#pragma unroll
        for (int mf = 0; mf < MFW; ++mf) {
            bf16x8 a[KS1];
#pragma unroll
            for (int ks = 0; ks < KS1; ++ks)
                a[ks] = *reinterpret_cast<const bf16x8*>(
                    &msg[(wm * MFW + mf) * 16 + (lane & 15)][ks * 32 + (lane >> 4) * 8]);
#pragma unroll
            for (int nt = 0; nt < NTW; ++nt)
#pragma unroll
                for (int ks = 0; ks < KS1; ++ks)
                    acc[mf][nt] = __builtin_amdgcn_mfma_f32_16x16x32_bf16(
                        a[ks], __builtin_bit_cast(bf16x8, b1[ks][nt]), acc[mf][nt], 0, 0, 0);
        }

        float bav[NTW];
#pragma unroll
        for (int nt = 0; nt < NTW; ++nt) bav[nt] = ba[(wn * NTW + nt) * 16 + (lane & 15)];

#pragma unroll
        for (int mf = 0; mf < MFW; ++mf)
#pragma unroll
            for (int nt = 0; nt < NTW; ++nt)
#pragma unroll
                for (int r = 0; r < 4; ++r) {
                    const float v = fmaxf(acc[mf][nt][r] + bav[nt], 0.0f);
                    hbuf[(wm * MFW + mf) * 16 + (lane >> 4) * 4 + r]
                        [(wn * NTW + nt) * 16 + (lane & 15)] = f2bf(v);
                }
    }
    __syncthreads();

    {   // GEMM2: out = relu(max_k(htile @ Wb) + bb)
        uint4 b2[KS2][NTW];
#pragma unroll
        for (int ks = 0; ks < KS2; ++ks)
#pragma unroll
            for (int nt = 0; nt < NTW; ++nt)
                b2[ks][nt] = fB[(ks * NT + wn * NTW + nt) * 64 + lane];

        f32x4v acc[MFW][NTW];
#pragma unroll
        for (int mf = 0; mf < MFW; ++mf)
#pragma unroll
            for (int nt = 0; nt < NTW; ++nt) acc[mf][nt] = (f32x4v)0.0f;

#pragma unroll
        for (int mf = 0; mf < MFW; ++mf) {
            bf16x8 a[KS2];
#pragma unroll
            for (int ks = 0; ks < KS2; ++ks)
                a[ks] = *reinterpret_cast<const bf16x8*>(
                    &hbuf[(wm * MFW + mf) * 16 + (lane & 15)][ks * 32 + (lane >> 4) * 8]);
#pragma unroll
            for (int nt = 0; nt < NTW; ++nt)
#pragma unroll
                for (int ks = 0; ks < KS2; ++ks)
                    acc[mf][nt] = __builtin_amdgcn_mfma_f32_16x16x32_bf16(
                        a[ks], __builtin_bit_cast(bf16x8, b2[ks][nt]), acc[mf][nt], 0, 0, 0);
        }

        float bbv[NTW];
#pragma unroll
        for (int nt = 0; nt < NTW; ++nt) bbv[nt] = bb[(wn * NTW + nt) * 16 + (lane & 15)];

#pragma unroll
        for (int mf = 0; mf < MFW; ++mf)
#pragma unroll
            for (int nt = 0; nt < NTW; ++nt) {
                const f32x4v t = acc[mf][nt];
                float m0 = fmaxf(fmaxf(t[0], t[1]), fmaxf(t[2], t[3]));
                m0 = fmaxf(m0, __shfl_xor(m0, 16));
                m0 = fmaxf(m0, __shfl_xor(m0, 32));
                const float v = fmaxf(m0 + bbv[nt], 0.0f);
                if (lane < 16)
                    out[(i0 + wm * MFW + mf) * COUT + (wn * NTW + nt) * 16 + lane] = v;
            }
    }
}

extern "C" void kernel_launch(void* const* d_in, const int* in_sizes, int n_in,
                              void* d_out, int out_size, void* d_ws, size_t ws_size,
                              hipStream_t stream)
{
    const float* pos = (const float*)d_in[0];
    const float* W1a = (const float*)d_in[1];
    const float* b1a = (const float*)d_in[2];
    const float* W1b = (const float*)d_in[3];
    const float* b1b = (const float*)d_in[4];
    const float* W2a = (const float*)d_in[5];
    const float* b2a = (const float*)d_in[6];
    const float* W2b = (const float*)d_in[7];
    const float* b2b = (const float*)d_in[8];
    const float* W3a = (const float*)d_in[9];
    const float* b3a = (const float*)d_in[10];
    const float* W3b = (const float*)d_in[11];
    const float* b3b = (const float*)d_in[12];

    float* out = (float*)d_out;
    float* h1 = out;                        // 8192 x 64
    float* h2 = out + N_PTS * 64;           // 8192 x 64
    float* h3 = out + N_PTS * 128;          // 8192 x 128

    int*   idx     = (int*)d_ws;                                   // 512 KB
    uint4* wsFrags = (uint4*)((char*)d_ws + N_PTS * KNN * 4);      // 88 KB

    // pos4 scratch in h3 region (dead before conv3 writes h3)
    float4* pos4 = (float4*)h3;

    prep_weights<<<88, 64, 0, stream>>>(W1a, W1b, W2a, W2b, W3a, W3b, wsFrags);
    prep_kernel<<<N_PTS / 256, 256, 0, stream>>>(pos, pos4);
    knn_kernel<<<N_PTS / QB, 256, 0, stream>>>(pos4, idx);

    const uint4* fW1a = wsFrags + 0 * 64;
    const uint4* fW1b = wsFrags + 4 * 64;
    const uint4* fW2a = wsFrags + 12 * 64;
    const uint4* fW2b = wsFrags + 24 * 64;
    const uint4* fW3a = wsFrags + 32 * 64;
    const uint4* fW3b = wsFrags + 56 * 64;

    conv_mfma<3, 64, 64, 4, 1><<<N_PTS / 8, 256, 0, stream>>>(
        pos, pos, idx, fW1a, b1a, fW1b, b1b, h1);
    conv_mfma<64, 64, 64, 4, 1><<<N_PTS / 8, 256, 0, stream>>>(
        h1, pos, idx, fW2a, b2a, fW2b, b2b, h2);
    conv_mfma<64, 128, 128, 2, 2><<<N_PTS / 8, 256, 0, stream>>>(
        h2, pos, idx, fW3a, b3a, fW3b, b3b, h3);
}